// Round 19
// baseline (347.330 us; speedup 1.0000x reference)
//
#include <hip/hip_runtime.h>

typedef _Float16 f16;
typedef _Float16 f16x4 __attribute__((ext_vector_type(4)));
typedef _Float16 f16x8 __attribute__((ext_vector_type(8)));
typedef __fp16 hf2 __attribute__((ext_vector_type(2)));
typedef float f32x4 __attribute__((ext_vector_type(4)));

#define DEV static __device__ __forceinline__

DEV void gl_lds16(const void* g, void* l) {
  __builtin_amdgcn_global_load_lds(
      (const __attribute__((address_space(1))) void*)g,
      (__attribute__((address_space(3))) void*)l, 16, 0, 0);
}

DEV uint pkrtz(float a, float b) {
  hf2 h = __builtin_amdgcn_cvt_pkrtz(a, b);
  return __builtin_bit_cast(uint, h);
}

DEV f32x4 MFMA(f16x8 a, f16x8 b, f32x4 c) {
  return __builtin_amdgcn_mfma_f32_16x16x32_f16(a, b, c, 0, 0, 0);
}

// (1/sqrt(128)) * log2(e) — folded into qr at the q-GEMM epilogue
#define SC2Q 0.12752551286084103f

// ---- 1) prep: x->f16 cast + LoRA-folded weight build ----
// W'[n][k] = w[n][k] + use_lora * sum_r A[k][r] * B[r][n], cast to f16.
__global__ __launch_bounds__(256) void prep_kernel(
    const float* __restrict__ x, f16* __restrict__ xb,
    const float* __restrict__ w0, const float* __restrict__ A0,
    const float* __restrict__ B0, f16* __restrict__ o0,
    const float* __restrict__ w1, const float* __restrict__ A1,
    const float* __restrict__ B1, f16* __restrict__ o1,
    const float* __restrict__ w2, const float* __restrict__ A2,
    const float* __restrict__ B2, f16* __restrict__ o2,
    const float* __restrict__ w3, const float* __restrict__ A3,
    const float* __restrict__ B3, f16* __restrict__ o3,
    const int* __restrict__ use_lora) {
  const float ul = (float)use_lora[0];
  const int gid = blockIdx.x * 256 + threadIdx.x;
  const int stride = gridDim.x * 256;
  const int XF4 = 2097152;  // 8.4M x elements / 4
  const int WF4 = 1048576;  // 4.2M weight elements / 4

  for (int i = gid; i < XF4; i += stride) {
    float4 v = ((const float4*)x)[i];
    f16x4 h = {(f16)v.x, (f16)v.y, (f16)v.z, (f16)v.w};
    ((f16x4*)xb)[i] = h;
  }

  const float* Ws[4] = {w0, w1, w2, w3};
  const float* As[4] = {A0, A1, A2, A3};
  const float* Bs[4] = {B0, B1, B2, B3};
  f16* Os[4] = {o0, o1, o2, o3};
#pragma unroll
  for (int wsel = 0; wsel < 4; ++wsel) {
    const float* W = Ws[wsel];
    const float* A = As[wsel];
    const float* Bm = Bs[wsel];
    f16* O = Os[wsel];
    for (int i = gid; i < WF4; i += stride) {
      const int n = i >> 9;            // 512 float4 per 2048-elem row
      const int k = (i & 511) << 2;
      float4 wv = ((const float4*)W)[i];
      float bcol[8];
#pragma unroll
      for (int r = 0; r < 8; ++r) bcol[r] = Bm[r * 2048 + n];
      const float4* Ap = (const float4*)(A + (size_t)k * 8);
      float ov[4];
      const float* wp = &wv.x;
#pragma unroll
      for (int j = 0; j < 4; ++j) {
        float4 a0 = Ap[j * 2], a1 = Ap[j * 2 + 1];
        float s = a0.x * bcol[0] + a0.y * bcol[1] + a0.z * bcol[2] +
                  a0.w * bcol[3] + a1.x * bcol[4] + a1.y * bcol[5] +
                  a1.z * bcol[6] + a1.w * bcol[7];
        ov[j] = wp[j] + ul * s;
      }
      f16x4 h = {(f16)ov[0], (f16)ov[1], (f16)ov[2], (f16)ov[3]};
      ((f16x4*)O)[i] = h;
    }
  }
}

// ------- 3) unified MFMA GEMM (R11-exact dbuf): 128x128, BK=64 --------
// 256 thr / 4 waves (2Mx2N, 64x64/wave); 2 blocks/CU (64KB LDS).
// One barrier per K-tile; stage issued right after barrier.
// mode 0: rope+SC2Q -> f16 qr [B,H,T,D]; mode 1: rope -> kr;
// mode 2: transpose -> f16 vt [B,H,D,T]; mode 3: fp32 -> d_out (LDS-staged).
struct GemmArgs {
  const f16* A;
  const f16* W[3];
  const float* bias[3];
  void* out[3];
  int mode[3];
};

__global__ __launch_bounds__(256, 2) void gemm2_kernel(
    GemmArgs args, const float* __restrict__ cosT,
    const float* __restrict__ sinT) {
  extern __shared__ char smem[];
  const int z = blockIdx.y;
  const f16* A = args.A;
  const f16* Bw = args.W[z];
  const float* bias = args.bias[z];
  void* out = args.out[z];
  const int mode = args.mode[z];

  const int tid = threadIdx.x;
  const int wave = tid >> 6, lane = tid & 63;
  const int lr = lane & 15, lg = lane >> 4;
  const int bm = (int)blockIdx.x >> 4, bn = (int)blockIdx.x & 15;
  const int m0 = bm << 7, n0 = bn << 7;
  const int wr = wave >> 1, wc = wave & 1;

  const char* Ab = (const char*)A;
  const char* Bb = (const char*)Bw;

  uint aoff[4], boff[4];
#pragma unroll
  for (int r = 0; r < 4; ++r) {
    uint beta = (uint)(wave * 4 + r) * 1024 + (uint)lane * 16;
    uint row = beta >> 7;
    uint c = (beta & 127u) ^ ((row & 7u) << 4);
    aoff[r] = (uint)(m0 + row) * 4096 + c;
    boff[r] = (uint)(n0 + row) * 4096 + c;
  }

  auto STAGE = [&](int kt, int b) {
    char* dst = smem + b * 32768;
    const size_t kb = (size_t)kt << 7;
#pragma unroll
    for (int r = 0; r < 4; ++r) {
      gl_lds16(Ab + (aoff[r] + kb), dst + (wave * 4 + r) * 1024);
      gl_lds16(Bb + (boff[r] + kb), dst + 16384 + (wave * 4 + r) * 1024);
    }
  };

  f32x4 acc[4][4] = {};

  STAGE(0, 0);
  for (int kt = 0; kt < 32; ++kt) {
    const int b = kt & 1;
    asm volatile("s_waitcnt vmcnt(0) lgkmcnt(0)" ::: "memory");
    __builtin_amdgcn_s_barrier();
    if (kt + 1 < 32) STAGE(kt + 1, b ^ 1);

    const char* buf = smem + b * 32768;
    f16x8 af[2][4], bf[2][4];
#pragma unroll
    for (int ks = 0; ks < 2; ++ks) {
#pragma unroll
      for (int mi = 0; mi < 4; ++mi) {
        int row = wr * 64 + mi * 16 + lr;
        int c = (ks * 64 + lg * 16) ^ ((row & 7) << 4);
        af[ks][mi] = *(const f16x8*)(buf + row * 128 + c);
      }
#pragma unroll
      for (int ni = 0; ni < 4; ++ni) {
        int row = wc * 64 + ni * 16 + lr;
        int c = (ks * 64 + lg * 16) ^ ((row & 7) << 4);
        bf[ks][ni] = *(const f16x8*)(buf + 16384 + row * 128 + c);
      }
    }
    __builtin_amdgcn_s_setprio(1);
#pragma unroll
    for (int ks = 0; ks < 2; ++ks)
#pragma unroll
      for (int mi = 0; mi < 4; ++mi)
#pragma unroll
        for (int ni = 0; ni < 4; ++ni)
          acc[mi][ni] = MFMA(af[ks][mi], bf[ks][ni], acc[mi][ni]);
    __builtin_amdgcn_s_setprio(0);
  }

  asm volatile("s_waitcnt lgkmcnt(0)" ::: "memory");
  __builtin_amdgcn_s_barrier();  // smem reusable for output staging

  float bv[4];
#pragma unroll
  for (int ni = 0; ni < 4; ++ni) bv[ni] = bias[n0 + wc * 64 + ni * 16 + lr];

#pragma unroll
  for (int mi = 0; mi < 4; ++mi) {
    const int mbase = m0 + wr * 64 + mi * 16 + lg * 4;
#pragma unroll
    for (int ni = 0; ni < 4; ++ni) {
      const int n = n0 + wc * 64 + ni * 16 + lr;
#pragma unroll
      for (int rg = 0; rg < 4; ++rg) {
        float v = acc[mi][ni][rg] + bv[ni];
        const int mm = wr * 64 + mi * 16 + lg * 4 + rg;  // tile-local t
        const int nn = wc * 64 + ni * 16 + lr;           // tile-local d
        if (mode <= 1) {
          float pv = __shfl_xor(v, 1);
          const int t = (mbase + rg) & 2047;
          const int ci = t * 64 + ((n & 127) >> 1);
          float cs = cosT[ci], sn = sinT[ci];
          float res = ((lane & 1) == 0) ? (v * cs - pv * sn)
                                        : (pv * sn + v * cs);
          if (mode == 0) res *= SC2Q;
          ((f16*)smem)[mm * 128 + nn] = (f16)res;
        } else if (mode == 2) {
          *(f16*)(smem + nn * 256 + ((mm * 2) ^ ((nn & 7) << 4))) = (f16)v;
        } else {
          // fp32 LDS staging (64KB, linear [mm][nn])
          ((float*)smem)[mm * 128 + nn] = v;
        }
      }
    }
  }

  if (mode <= 1) {
    __builtin_amdgcn_s_barrier();
    const long b_ = m0 >> 11;
    const int tb = m0 & 2047;
    char* obase = (char*)out + ((b_ * 16 + bn) * 2048 + tb) * 256;
#pragma unroll
    for (int p = 0; p < 8; ++p) {
      int s = p * 4096 + tid * 16;
      int row = s >> 8, c = s & 255;
      *(uint4*)(obase + (long)row * 256 + c) = *(const uint4*)(smem + s);
    }
  } else if (mode == 2) {
    __builtin_amdgcn_s_barrier();
    const long b_ = m0 >> 11;
    const int tb = m0 & 2047;
    char* obase = (char*)out + (((b_ * 16 + bn) * 128) * 2048 + tb) * 2;
#pragma unroll
    for (int p = 0; p < 8; ++p) {
      int s = p * 4096 + tid * 16;
      int row = s >> 8, cb = s & 255;
      int c = cb ^ ((row & 7) << 4);
      uint4 val = *(const uint4*)(smem + row * 256 + c);
      *(uint4*)(obase + (long)row * 4096 + cb) = val;
    }
  } else {
    // mode 3: coalesced fp32 tile store, 128 rows x 512B
    __builtin_amdgcn_s_barrier();
    char* obase = (char*)out + ((long)m0 * 2048 + n0) * 4;
#pragma unroll
    for (int p = 0; p < 16; ++p) {
      int s = p * 4096 + tid * 16;
      int row = s >> 9, cb = s & 511;
      *(uint4*)(obase + (long)row * 8192 + cb) = *(const uint4*)(smem + s);
    }
  }
}

// ---------- 5) causal flash attention (R10 verbatim: 123.4us verified) ------
__global__ __launch_bounds__(256, 2) void attn_kernel(
    const f16* __restrict__ qr, const f16* __restrict__ kr,
    const f16* __restrict__ vt, f16* __restrict__ y) {
  extern __shared__ char smem[];  // 2 x (K 16KB + V 16KB) = 64KB
  const int tid = threadIdx.x, wave = tid >> 6, lane = tid & 63;
  const int lr = lane & 15, lg = lane >> 4;
  const int qt = 15 - (int)blockIdx.x;  // longest blocks dispatch first
  const int q0 = qt << 7;
  const int h = blockIdx.y, b = blockIdx.z;
  const long bh = b * 16 + h;
  const int nt = 2 * qt + 2;

  const char* kbase = (const char*)kr + bh * 2048 * 256;
  const char* vbase = (const char*)vt + bh * 128 * 4096;

  uint koff[4], voff[4];
#pragma unroll
  for (int r = 0; r < 4; ++r) {
    uint s = (uint)(wave * 4 + r) * 1024 + (uint)lane * 16;
    uint rowk = s >> 8;
    koff[r] = rowk * 256 + ((s & 255u) ^ ((rowk & 7u) << 4));
    uint rowv = s >> 7;
    voff[r] = rowv * 4096 + ((s & 127u) ^ ((rowv & 7u) << 4));
  }

  f16x8 qf[2][4];
#pragma unroll
  for (int g = 0; g < 2; ++g) {
    const char* qb =
        (const char*)qr + (bh * 2048 + q0 + wave * 32 + g * 16 + lr) * 256;
#pragma unroll
    for (int ks = 0; ks < 4; ++ks)
      qf[g][ks] = *(const f16x8*)(qb + ks * 64 + lg * 16);
  }

  f32x4 o[2][8] = {};
  float mrow[2] = {-3e38f, -3e38f};
  float lsum[2] = {0.f, 0.f};

  auto STAGE = [&](int kv0, int bsel) {
    char* Ks = smem + bsel * 32768;
    char* Vs = Ks + 16384;
#pragma unroll
    for (int r = 0; r < 4; ++r) {
      gl_lds16(kbase + (size_t)kv0 * 256 + koff[r], Ks + (wave * 4 + r) * 1024);
      gl_lds16(vbase + (size_t)kv0 * 2 + voff[r], Vs + (wave * 4 + r) * 1024);
    }
  };

  STAGE(0, 0);
  __syncthreads();

  for (int kt = 0; kt < nt; ++kt) {
    const int kv0 = kt << 6;
    if (kt + 1 < nt) STAGE((kt + 1) << 6, (kt + 1) & 1);
    const char* Ks = smem + (kt & 1) * 32768;
    const char* Vs = Ks + 16384;

    if (kv0 <= q0 + wave * 32 + 31) {
      f32x4 sa[2][4] = {};
      __builtin_amdgcn_s_setprio(1);
#pragma unroll
      for (int ks = 0; ks < 4; ++ks)
#pragma unroll
        for (int n = 0; n < 4; ++n) {
          int row = n * 16 + lr;
          int c = (ks * 64 + lg * 16) ^ ((row & 7) << 4);
          f16x8 kf = *(const f16x8*)(Ks + row * 256 + c);
          sa[0][n] = MFMA(kf, qf[0][ks], sa[0][n]);
          sa[1][n] = MFMA(kf, qf[1][ks], sa[1][n]);
        }
      __builtin_amdgcn_s_setprio(0);

      f16x8 pf[2][2];
#pragma unroll
      for (int g = 0; g < 2; ++g) {
        const int qgbase = q0 + wave * 32 + g * 16;
        float L[16];
        const bool dm = (kv0 + 63 > qgbase);
#pragma unroll
        for (int n = 0; n < 4; ++n)
#pragma unroll
          for (int rg = 0; rg < 4; ++rg) {
            float Lv = sa[g][n][rg];  // q pre-scaled: log2 units
            if (dm && (kv0 + n * 16 + lg * 4 + rg > qgbase + lr)) Lv = -3e37f;
            L[n * 4 + rg] = Lv;
          }
        float m0a = fmaxf(L[0], L[1]),  m1a = fmaxf(L[2], L[3]);
        float m2a = fmaxf(L[4], L[5]),  m3a = fmaxf(L[6], L[7]);
        float m4a = fmaxf(L[8], L[9]),  m5a = fmaxf(L[10], L[11]);
        float m6a = fmaxf(L[12], L[13]), m7a = fmaxf(L[14], L[15]);
        float m0b = fmaxf(m0a, m1a), m1b = fmaxf(m2a, m3a);
        float m2b = fmaxf(m4a, m5a), m3b = fmaxf(m6a, m7a);
        float pm = fmaxf(fmaxf(m0b, m1b), fmaxf(m2b, m3b));
        if (!__all(pm <= mrow[g] + 8.f)) {
          pm = fmaxf(pm, __shfl_xor(pm, 16));
          pm = fmaxf(pm, __shfl_xor(pm, 32));
          float mn = fmaxf(mrow[g], pm);
          float alpha = exp2f(mrow[g] - mn);
          mrow[g] = mn;
          lsum[g] *= alpha;
#pragma unroll
          for (int dt = 0; dt < 8; ++dt)
#pragma unroll
            for (int rg = 0; rg < 4; ++rg) o[g][dt][rg] *= alpha;
        }
        const float mn = mrow[g];
#pragma unroll
        for (int i = 0; i < 16; ++i) L[i] = exp2f(L[i] - mn);
        float s0 = L[0] + L[1], s1 = L[2] + L[3], s2 = L[4] + L[5],
              s3 = L[6] + L[7], s4 = L[8] + L[9], s5 = L[10] + L[11],
              s6 = L[12] + L[13], s7 = L[14] + L[15];
        float t0 = s0 + s1, t1 = s2 + s3, t2 = s4 + s5, t3 = s6 + s7;
        float ps = (t0 + t1) + (t2 + t3);
        ps += __shfl_xor(ps, 16);
        ps += __shfl_xor(ps, 32);
        lsum[g] += ps;

#pragma unroll
        for (int ks2 = 0; ks2 < 2; ++ks2) {
          uint w0 = pkrtz(L[8 * ks2 + 0], L[8 * ks2 + 1]);
          uint w1 = pkrtz(L[8 * ks2 + 2], L[8 * ks2 + 3]);
          uint w2 = pkrtz(L[8 * ks2 + 4], L[8 * ks2 + 5]);
          uint w3 = pkrtz(L[8 * ks2 + 6], L[8 * ks2 + 7]);
          int src1 = ((lg & 1) << 5) + lr;
          int src2 = src1 + 16;
          uint a0 = __shfl((int)w0, src1), a1 = __shfl((int)w1, src1);
          uint a2 = __shfl((int)w2, src1), a3 = __shfl((int)w3, src1);
          uint b0 = __shfl((int)w0, src2), b1 = __shfl((int)w1, src2);
          uint b2 = __shfl((int)w2, src2), b3 = __shfl((int)w3, src2);
          const bool hi = (lg >> 1) != 0;
          uint4 uu;
          uu.x = hi ? a2 : a0;
          uu.y = hi ? a3 : a1;
          uu.z = hi ? b2 : b0;
          uu.w = hi ? b3 : b1;
          pf[g][ks2] = __builtin_bit_cast(f16x8, uu);
        }
      }

#pragma unroll
      for (int ks2 = 0; ks2 < 2; ++ks2) {
        __builtin_amdgcn_s_setprio(1);
#pragma unroll
        for (int dt = 0; dt < 8; ++dt) {
          int drow = dt * 16 + lr;
          int c = (ks2 * 64 + lg * 16) ^ ((drow & 7) << 4);
          f16x8 vf = *(const f16x8*)(Vs + drow * 128 + c);
          o[0][dt] = MFMA(vf, pf[0][ks2], o[0][dt]);
          o[1][dt] = MFMA(vf, pf[1][ks2], o[1][dt]);
        }
        __builtin_amdgcn_s_setprio(0);
      }
    }
    __syncthreads();
  }

#pragma unroll
  for (int g = 0; g < 2; ++g) {
    const float inv = 1.f / lsum[g];
    const int row = wave * 32 + g * 16 + lr;
#pragma unroll
    for (int dt = 0; dt < 8; ++dt) {
      uint lo = pkrtz(o[g][dt][0] * inv, o[g][dt][1] * inv);
      uint hi2 = pkrtz(o[g][dt][2] * inv, o[g][dt][3] * inv);
      int c = (dt * 32 + lg * 8) ^ ((row & 7) << 4);
      uint2 w;
      w.x = lo;
      w.y = hi2;
      *(uint2*)(smem + row * 256 + c) = w;
    }
  }
  __syncthreads();
#pragma unroll
  for (int p = 0; p < 8; ++p) {
    int s = p * 4096 + tid * 16;
    int row = s >> 8, cb = s & 255;
    int c = cb ^ ((row & 7) << 4);
    char* dst =
        (char*)y + ((long)(b * 2048 + q0 + row) * 2048 + h * 128) * 2 + cb;
    *(uint4*)dst = *(const uint4*)(smem + row * 256 + c);
  }
}

// ---------------- launch ----------------
extern "C" void kernel_launch(void* const* d_in, const int* in_sizes, int n_in,
                              void* d_out, int out_size, void* d_ws,
                              size_t ws_size, hipStream_t stream) {
  (void)in_sizes; (void)n_in; (void)out_size; (void)ws_size;
  const float* x   = (const float*)d_in[0];
  const float* q_w = (const float*)d_in[1];
  const float* q_b = (const float*)d_in[2];
  const float* q_A = (const float*)d_in[3];
  const float* q_B = (const float*)d_in[4];
  const float* k_w = (const float*)d_in[5];
  const float* k_b = (const float*)d_in[6];
  const float* k_A = (const float*)d_in[7];
  const float* k_B = (const float*)d_in[8];
  const float* v_w = (const float*)d_in[9];
  const float* v_b = (const float*)d_in[10];
  const float* v_A = (const float*)d_in[11];
  const float* v_B = (const float*)d_in[12];
  const float* p_w = (const float*)d_in[13];
  const float* p_b = (const float*)d_in[14];
  const float* p_A = (const float*)d_in[15];
  const float* p_B = (const float*)d_in[16];
  const float* cosT = (const float*)d_in[17];
  const float* sinT = (const float*)d_in[18];
  const int* use_lora = (const int*)d_in[20];  // mask (19) implicit: causal

  char* ws = (char*)d_ws;
  f16* xb  = (f16*)(ws);                    // [B,T,C] f16 ; reused as y later
  f16* wqb = (f16*)(ws + 16777216);         // W'_q (LoRA-folded)
  f16* wkb = (f16*)(ws + 25165824);
  f16* wvb = (f16*)(ws + 33554432);
  f16* wpb = (f16*)(ws + 41943040);
  f16* qr  = (f16*)(ws + 50855936);         // [B,H,T,D]
  f16* kr  = (f16*)(ws + 67633152);         // [B,H,T,D]
  f16* vt  = (f16*)(ws + 84410368);         // [B,H,D,T] (direct from v-GEMM)
  f16* y   = xb;                            // aliases xb (dead after qkv GEMM)

  prep_kernel<<<dim3(2048), dim3(256), 0, stream>>>(
      x, xb, q_w, q_A, q_B, wqb, k_w, k_A, k_B, wkb, v_w, v_A, v_B, wvb, p_w,
      p_A, p_B, wpb, use_lora);

  GemmArgs qkv;
  qkv.A = xb;
  qkv.W[0] = wqb;  qkv.W[1] = wkb;  qkv.W[2] = wvb;
  qkv.bias[0] = q_b; qkv.bias[1] = k_b; qkv.bias[2] = v_b;
  qkv.out[0] = qr; qkv.out[1] = kr; qkv.out[2] = vt;
  qkv.mode[0] = 0; qkv.mode[1] = 1; qkv.mode[2] = 2;
  gemm2_kernel<<<dim3(512, 3), dim3(256), 65536, stream>>>(qkv, cosT, sinT);

  attn_kernel<<<dim3(16, 16, 2), dim3(256), 65536, stream>>>(qr, kr, vt, y);

  GemmArgs pp;
  pp.A = y;
  pp.W[0] = wpb;  pp.W[1] = wpb;  pp.W[2] = wpb;
  pp.bias[0] = p_b; pp.bias[1] = p_b; pp.bias[2] = p_b;
  pp.out[0] = d_out; pp.out[1] = d_out; pp.out[2] = d_out;
  pp.mode[0] = 3; pp.mode[1] = 3; pp.mode[2] = 3;
  gemm2_kernel<<<dim3(512, 1), dim3(256), 65536, stream>>>(pp, nullptr,
                                                           nullptr);
}

// Round 20
// 344.878 us; speedup vs baseline: 1.0071x; 1.0071x over previous
//
#include <hip/hip_runtime.h>

typedef _Float16 f16;
typedef _Float16 f16x4 __attribute__((ext_vector_type(4)));
typedef _Float16 f16x8 __attribute__((ext_vector_type(8)));
typedef __fp16 hf2 __attribute__((ext_vector_type(2)));
typedef float f32x4 __attribute__((ext_vector_type(4)));

#define DEV static __device__ __forceinline__

DEV void gl_lds16(const void* g, void* l) {
  __builtin_amdgcn_global_load_lds(
      (const __attribute__((address_space(1))) void*)g,
      (__attribute__((address_space(3))) void*)l, 16, 0, 0);
}

DEV uint pkrtz(float a, float b) {
  hf2 h = __builtin_amdgcn_cvt_pkrtz(a, b);
  return __builtin_bit_cast(uint, h);
}

DEV f32x4 MFMA(f16x8 a, f16x8 b, f32x4 c) {
  return __builtin_amdgcn_mfma_f32_16x16x32_f16(a, b, c, 0, 0, 0);
}

// (1/sqrt(128)) * log2(e) — folded into qr at the q-GEMM epilogue
#define SC2Q 0.12752551286084103f

// ---- 1) prep: x->f16 cast + LoRA-folded weight build ----
// W'[n][k] = w[n][k] + use_lora * sum_r A[k][r] * B[r][n], cast to f16.
__global__ __launch_bounds__(256) void prep_kernel(
    const float* __restrict__ x, f16* __restrict__ xb,
    const float* __restrict__ w0, const float* __restrict__ A0,
    const float* __restrict__ B0, f16* __restrict__ o0,
    const float* __restrict__ w1, const float* __restrict__ A1,
    const float* __restrict__ B1, f16* __restrict__ o1,
    const float* __restrict__ w2, const float* __restrict__ A2,
    const float* __restrict__ B2, f16* __restrict__ o2,
    const float* __restrict__ w3, const float* __restrict__ A3,
    const float* __restrict__ B3, f16* __restrict__ o3,
    const int* __restrict__ use_lora) {
  const float ul = (float)use_lora[0];
  const int gid = blockIdx.x * 256 + threadIdx.x;
  const int stride = gridDim.x * 256;
  const int XF4 = 2097152;  // 8.4M x elements / 4
  const int WF4 = 1048576;  // 4.2M weight elements / 4

  for (int i = gid; i < XF4; i += stride) {
    float4 v = ((const float4*)x)[i];
    f16x4 h = {(f16)v.x, (f16)v.y, (f16)v.z, (f16)v.w};
    ((f16x4*)xb)[i] = h;
  }

  const float* Ws[4] = {w0, w1, w2, w3};
  const float* As[4] = {A0, A1, A2, A3};
  const float* Bs[4] = {B0, B1, B2, B3};
  f16* Os[4] = {o0, o1, o2, o3};
#pragma unroll
  for (int wsel = 0; wsel < 4; ++wsel) {
    const float* W = Ws[wsel];
    const float* A = As[wsel];
    const float* Bm = Bs[wsel];
    f16* O = Os[wsel];
    for (int i = gid; i < WF4; i += stride) {
      const int n = i >> 9;            // 512 float4 per 2048-elem row
      const int k = (i & 511) << 2;
      float4 wv = ((const float4*)W)[i];
      float bcol[8];
#pragma unroll
      for (int r = 0; r < 8; ++r) bcol[r] = Bm[r * 2048 + n];
      const float4* Ap = (const float4*)(A + (size_t)k * 8);
      float ov[4];
      const float* wp = &wv.x;
#pragma unroll
      for (int j = 0; j < 4; ++j) {
        float4 a0 = Ap[j * 2], a1 = Ap[j * 2 + 1];
        float s = a0.x * bcol[0] + a0.y * bcol[1] + a0.z * bcol[2] +
                  a0.w * bcol[3] + a1.x * bcol[4] + a1.y * bcol[5] +
                  a1.z * bcol[6] + a1.w * bcol[7];
        ov[j] = wp[j] + ul * s;
      }
      f16x4 h = {(f16)ov[0], (f16)ov[1], (f16)ov[2], (f16)ov[3]};
      ((f16x4*)O)[i] = h;
    }
  }
}

// ------- 3) unified MFMA GEMM (R11-exact dbuf): 128x128, BK=64 --------
// 256 thr / 4 waves (2Mx2N, 64x64/wave); 2 blocks/CU (64KB LDS).
// One barrier per K-tile; stage issued right after barrier.
// mode 0: rope+SC2Q -> f16 qr [B,H,T,D]; mode 1: rope -> kr;
// mode 2: transpose -> f16 vt [B,H,D,T]; mode 3: fp32 -> d_out.
struct GemmArgs {
  const f16* A;
  const f16* W[3];
  const float* bias[3];
  void* out[3];
  int mode[3];
};

__global__ __launch_bounds__(256, 2) void gemm2_kernel(
    GemmArgs args, const float* __restrict__ cosT,
    const float* __restrict__ sinT) {
  extern __shared__ char smem[];
  const int z = blockIdx.y;
  const f16* A = args.A;
  const f16* Bw = args.W[z];
  const float* bias = args.bias[z];
  void* out = args.out[z];
  const int mode = args.mode[z];

  const int tid = threadIdx.x;
  const int wave = tid >> 6, lane = tid & 63;
  const int lr = lane & 15, lg = lane >> 4;
  const int bm = (int)blockIdx.x >> 4, bn = (int)blockIdx.x & 15;
  const int m0 = bm << 7, n0 = bn << 7;
  const int wr = wave >> 1, wc = wave & 1;

  const char* Ab = (const char*)A;
  const char* Bb = (const char*)Bw;

  uint aoff[4], boff[4];
#pragma unroll
  for (int r = 0; r < 4; ++r) {
    uint beta = (uint)(wave * 4 + r) * 1024 + (uint)lane * 16;
    uint row = beta >> 7;
    uint c = (beta & 127u) ^ ((row & 7u) << 4);
    aoff[r] = (uint)(m0 + row) * 4096 + c;
    boff[r] = (uint)(n0 + row) * 4096 + c;
  }

  auto STAGE = [&](int kt, int b) {
    char* dst = smem + b * 32768;
    const size_t kb = (size_t)kt << 7;
#pragma unroll
    for (int r = 0; r < 4; ++r) {
      gl_lds16(Ab + (aoff[r] + kb), dst + (wave * 4 + r) * 1024);
      gl_lds16(Bb + (boff[r] + kb), dst + 16384 + (wave * 4 + r) * 1024);
    }
  };

  f32x4 acc[4][4] = {};

  STAGE(0, 0);
  for (int kt = 0; kt < 32; ++kt) {
    const int b = kt & 1;
    asm volatile("s_waitcnt vmcnt(0) lgkmcnt(0)" ::: "memory");
    __builtin_amdgcn_s_barrier();
    if (kt + 1 < 32) STAGE(kt + 1, b ^ 1);

    const char* buf = smem + b * 32768;
    f16x8 af[2][4], bf[2][4];
#pragma unroll
    for (int ks = 0; ks < 2; ++ks) {
#pragma unroll
      for (int mi = 0; mi < 4; ++mi) {
        int row = wr * 64 + mi * 16 + lr;
        int c = (ks * 64 + lg * 16) ^ ((row & 7) << 4);
        af[ks][mi] = *(const f16x8*)(buf + row * 128 + c);
      }
#pragma unroll
      for (int ni = 0; ni < 4; ++ni) {
        int row = wc * 64 + ni * 16 + lr;
        int c = (ks * 64 + lg * 16) ^ ((row & 7) << 4);
        bf[ks][ni] = *(const f16x8*)(buf + 16384 + row * 128 + c);
      }
    }
    __builtin_amdgcn_s_setprio(1);
#pragma unroll
    for (int ks = 0; ks < 2; ++ks)
#pragma unroll
      for (int mi = 0; mi < 4; ++mi)
#pragma unroll
        for (int ni = 0; ni < 4; ++ni)
          acc[mi][ni] = MFMA(af[ks][mi], bf[ks][ni], acc[mi][ni]);
    __builtin_amdgcn_s_setprio(0);
  }

  asm volatile("s_waitcnt lgkmcnt(0)" ::: "memory");
  __builtin_amdgcn_s_barrier();  // smem reusable for output staging

  float bv[4];
#pragma unroll
  for (int ni = 0; ni < 4; ++ni) bv[ni] = bias[n0 + wc * 64 + ni * 16 + lr];

#pragma unroll
  for (int mi = 0; mi < 4; ++mi) {
    const int mbase = m0 + wr * 64 + mi * 16 + lg * 4;
#pragma unroll
    for (int ni = 0; ni < 4; ++ni) {
      const int n = n0 + wc * 64 + ni * 16 + lr;
#pragma unroll
      for (int rg = 0; rg < 4; ++rg) {
        float v = acc[mi][ni][rg] + bv[ni];
        const int mm = wr * 64 + mi * 16 + lg * 4 + rg;  // tile-local t
        const int nn = wc * 64 + ni * 16 + lr;           // tile-local d
        if (mode <= 1) {
          float pv = __shfl_xor(v, 1);
          const int t = (mbase + rg) & 2047;
          const int ci = t * 64 + ((n & 127) >> 1);
          float cs = cosT[ci], sn = sinT[ci];
          float res = ((lane & 1) == 0) ? (v * cs - pv * sn)
                                        : (pv * sn + v * cs);
          if (mode == 0) res *= SC2Q;
          ((f16*)smem)[mm * 128 + nn] = (f16)res;
        } else if (mode == 2) {
          *(f16*)(smem + nn * 256 + ((mm * 2) ^ ((nn & 7) << 4))) = (f16)v;
        } else {
          ((float*)out)[(size_t)(mbase + rg) * 2048 + n] = v;
        }
      }
    }
  }

  if (mode <= 1) {
    __builtin_amdgcn_s_barrier();
    const long b_ = m0 >> 11;
    const int tb = m0 & 2047;
    char* obase = (char*)out + ((b_ * 16 + bn) * 2048 + tb) * 256;
#pragma unroll
    for (int p = 0; p < 8; ++p) {
      int s = p * 4096 + tid * 16;
      int row = s >> 8, c = s & 255;
      *(uint4*)(obase + (long)row * 256 + c) = *(const uint4*)(smem + s);
    }
  } else if (mode == 2) {
    __builtin_amdgcn_s_barrier();
    const long b_ = m0 >> 11;
    const int tb = m0 & 2047;
    char* obase = (char*)out + (((b_ * 16 + bn) * 128) * 2048 + tb) * 2;
#pragma unroll
    for (int p = 0; p < 8; ++p) {
      int s = p * 4096 + tid * 16;
      int row = s >> 8, cb = s & 255;
      int c = cb ^ ((row & 7) << 4);
      uint4 val = *(const uint4*)(smem + row * 256 + c);
      *(uint4*)(obase + (long)row * 4096 + cb) = val;
    }
  }
}

// ---------- 5) causal flash attention (R10 verbatim: 123.4us verified) ------
__global__ __launch_bounds__(256, 2) void attn_kernel(
    const f16* __restrict__ qr, const f16* __restrict__ kr,
    const f16* __restrict__ vt, f16* __restrict__ y) {
  extern __shared__ char smem[];  // 2 x (K 16KB + V 16KB) = 64KB
  const int tid = threadIdx.x, wave = tid >> 6, lane = tid & 63;
  const int lr = lane & 15, lg = lane >> 4;
  const int qt = 15 - (int)blockIdx.x;  // longest blocks dispatch first
  const int q0 = qt << 7;
  const int h = blockIdx.y, b = blockIdx.z;
  const long bh = b * 16 + h;
  const int nt = 2 * qt + 2;

  const char* kbase = (const char*)kr + bh * 2048 * 256;
  const char* vbase = (const char*)vt + bh * 128 * 4096;

  uint koff[4], voff[4];
#pragma unroll
  for (int r = 0; r < 4; ++r) {
    uint s = (uint)(wave * 4 + r) * 1024 + (uint)lane * 16;
    uint rowk = s >> 8;
    koff[r] = rowk * 256 + ((s & 255u) ^ ((rowk & 7u) << 4));
    uint rowv = s >> 7;
    voff[r] = rowv * 4096 + ((s & 127u) ^ ((rowv & 7u) << 4));
  }

  f16x8 qf[2][4];
#pragma unroll
  for (int g = 0; g < 2; ++g) {
    const char* qb =
        (const char*)qr + (bh * 2048 + q0 + wave * 32 + g * 16 + lr) * 256;
#pragma unroll
    for (int ks = 0; ks < 4; ++ks)
      qf[g][ks] = *(const f16x8*)(qb + ks * 64 + lg * 16);
  }

  f32x4 o[2][8] = {};
  float mrow[2] = {-3e38f, -3e38f};
  float lsum[2] = {0.f, 0.f};

  auto STAGE = [&](int kv0, int bsel) {
    char* Ks = smem + bsel * 32768;
    char* Vs = Ks + 16384;
#pragma unroll
    for (int r = 0; r < 4; ++r) {
      gl_lds16(kbase + (size_t)kv0 * 256 + koff[r], Ks + (wave * 4 + r) * 1024);
      gl_lds16(vbase + (size_t)kv0 * 2 + voff[r], Vs + (wave * 4 + r) * 1024);
    }
  };

  STAGE(0, 0);
  __syncthreads();

  for (int kt = 0; kt < nt; ++kt) {
    const int kv0 = kt << 6;
    if (kt + 1 < nt) STAGE((kt + 1) << 6, (kt + 1) & 1);
    const char* Ks = smem + (kt & 1) * 32768;
    const char* Vs = Ks + 16384;

    if (kv0 <= q0 + wave * 32 + 31) {
      f32x4 sa[2][4] = {};
      __builtin_amdgcn_s_setprio(1);
#pragma unroll
      for (int ks = 0; ks < 4; ++ks)
#pragma unroll
        for (int n = 0; n < 4; ++n) {
          int row = n * 16 + lr;
          int c = (ks * 64 + lg * 16) ^ ((row & 7) << 4);
          f16x8 kf = *(const f16x8*)(Ks + row * 256 + c);
          sa[0][n] = MFMA(kf, qf[0][ks], sa[0][n]);
          sa[1][n] = MFMA(kf, qf[1][ks], sa[1][n]);
        }
      __builtin_amdgcn_s_setprio(0);

      f16x8 pf[2][2];
#pragma unroll
      for (int g = 0; g < 2; ++g) {
        const int qgbase = q0 + wave * 32 + g * 16;
        float L[16];
        const bool dm = (kv0 + 63 > qgbase);
#pragma unroll
        for (int n = 0; n < 4; ++n)
#pragma unroll
          for (int rg = 0; rg < 4; ++rg) {
            float Lv = sa[g][n][rg];  // q pre-scaled: log2 units
            if (dm && (kv0 + n * 16 + lg * 4 + rg > qgbase + lr)) Lv = -3e37f;
            L[n * 4 + rg] = Lv;
          }
        float m0a = fmaxf(L[0], L[1]),  m1a = fmaxf(L[2], L[3]);
        float m2a = fmaxf(L[4], L[5]),  m3a = fmaxf(L[6], L[7]);
        float m4a = fmaxf(L[8], L[9]),  m5a = fmaxf(L[10], L[11]);
        float m6a = fmaxf(L[12], L[13]), m7a = fmaxf(L[14], L[15]);
        float m0b = fmaxf(m0a, m1a), m1b = fmaxf(m2a, m3a);
        float m2b = fmaxf(m4a, m5a), m3b = fmaxf(m6a, m7a);
        float pm = fmaxf(fmaxf(m0b, m1b), fmaxf(m2b, m3b));
        if (!__all(pm <= mrow[g] + 8.f)) {
          pm = fmaxf(pm, __shfl_xor(pm, 16));
          pm = fmaxf(pm, __shfl_xor(pm, 32));
          float mn = fmaxf(mrow[g], pm);
          float alpha = exp2f(mrow[g] - mn);
          mrow[g] = mn;
          lsum[g] *= alpha;
#pragma unroll
          for (int dt = 0; dt < 8; ++dt)
#pragma unroll
            for (int rg = 0; rg < 4; ++rg) o[g][dt][rg] *= alpha;
        }
        const float mn = mrow[g];
#pragma unroll
        for (int i = 0; i < 16; ++i) L[i] = exp2f(L[i] - mn);
        float s0 = L[0] + L[1], s1 = L[2] + L[3], s2 = L[4] + L[5],
              s3 = L[6] + L[7], s4 = L[8] + L[9], s5 = L[10] + L[11],
              s6 = L[12] + L[13], s7 = L[14] + L[15];
        float t0 = s0 + s1, t1 = s2 + s3, t2 = s4 + s5, t3 = s6 + s7;
        float ps = (t0 + t1) + (t2 + t3);
        ps += __shfl_xor(ps, 16);
        ps += __shfl_xor(ps, 32);
        lsum[g] += ps;

#pragma unroll
        for (int ks2 = 0; ks2 < 2; ++ks2) {
          uint w0 = pkrtz(L[8 * ks2 + 0], L[8 * ks2 + 1]);
          uint w1 = pkrtz(L[8 * ks2 + 2], L[8 * ks2 + 3]);
          uint w2 = pkrtz(L[8 * ks2 + 4], L[8 * ks2 + 5]);
          uint w3 = pkrtz(L[8 * ks2 + 6], L[8 * ks2 + 7]);
          int src1 = ((lg & 1) << 5) + lr;
          int src2 = src1 + 16;
          uint a0 = __shfl((int)w0, src1), a1 = __shfl((int)w1, src1);
          uint a2 = __shfl((int)w2, src1), a3 = __shfl((int)w3, src1);
          uint b0 = __shfl((int)w0, src2), b1 = __shfl((int)w1, src2);
          uint b2 = __shfl((int)w2, src2), b3 = __shfl((int)w3, src2);
          const bool hi = (lg >> 1) != 0;
          uint4 uu;
          uu.x = hi ? a2 : a0;
          uu.y = hi ? a3 : a1;
          uu.z = hi ? b2 : b0;
          uu.w = hi ? b3 : b1;
          pf[g][ks2] = __builtin_bit_cast(f16x8, uu);
        }
      }

#pragma unroll
      for (int ks2 = 0; ks2 < 2; ++ks2) {
        __builtin_amdgcn_s_setprio(1);
#pragma unroll
        for (int dt = 0; dt < 8; ++dt) {
          int drow = dt * 16 + lr;
          int c = (ks2 * 64 + lg * 16) ^ ((drow & 7) << 4);
          f16x8 vf = *(const f16x8*)(Vs + drow * 128 + c);
          o[0][dt] = MFMA(vf, pf[0][ks2], o[0][dt]);
          o[1][dt] = MFMA(vf, pf[1][ks2], o[1][dt]);
        }
        __builtin_amdgcn_s_setprio(0);
      }
    }
    __syncthreads();
  }

#pragma unroll
  for (int g = 0; g < 2; ++g) {
    const float inv = 1.f / lsum[g];
    const int row = wave * 32 + g * 16 + lr;
#pragma unroll
    for (int dt = 0; dt < 8; ++dt) {
      uint lo = pkrtz(o[g][dt][0] * inv, o[g][dt][1] * inv);
      uint hi2 = pkrtz(o[g][dt][2] * inv, o[g][dt][3] * inv);
      int c = (dt * 32 + lg * 8) ^ ((row & 7) << 4);
      uint2 w;
      w.x = lo;
      w.y = hi2;
      *(uint2*)(smem + row * 256 + c) = w;
    }
  }
  __syncthreads();
#pragma unroll
  for (int p = 0; p < 8; ++p) {
    int s = p * 4096 + tid * 16;
    int row = s >> 8, cb = s & 255;
    int c = cb ^ ((row & 7) << 4);
    char* dst =
        (char*)y + ((long)(b * 2048 + q0 + row) * 2048 + h * 128) * 2 + cb;
    *(uint4*)dst = *(const uint4*)(smem + row * 256 + c);
  }
}

// ---------------- launch ----------------
extern "C" void kernel_launch(void* const* d_in, const int* in_sizes, int n_in,
                              void* d_out, int out_size, void* d_ws,
                              size_t ws_size, hipStream_t stream) {
  (void)in_sizes; (void)n_in; (void)out_size; (void)ws_size;
  const float* x   = (const float*)d_in[0];
  const float* q_w = (const float*)d_in[1];
  const float* q_b = (const float*)d_in[2];
  const float* q_A = (const float*)d_in[3];
  const float* q_B = (const float*)d_in[4];
  const float* k_w = (const float*)d_in[5];
  const float* k_b = (const float*)d_in[6];
  const float* k_A = (const float*)d_in[7];
  const float* k_B = (const float*)d_in[8];
  const float* v_w = (const float*)d_in[9];
  const float* v_b = (const float*)d_in[10];
  const float* v_A = (const float*)d_in[11];
  const float* v_B = (const float*)d_in[12];
  const float* p_w = (const float*)d_in[13];
  const float* p_b = (const float*)d_in[14];
  const float* p_A = (const float*)d_in[15];
  const float* p_B = (const float*)d_in[16];
  const float* cosT = (const float*)d_in[17];
  const float* sinT = (const float*)d_in[18];
  const int* use_lora = (const int*)d_in[20];  // mask (19) implicit: causal

  char* ws = (char*)d_ws;
  f16* xb  = (f16*)(ws);                    // [B,T,C] f16 ; reused as y later
  f16* wqb = (f16*)(ws + 16777216);         // W'_q (LoRA-folded)
  f16* wkb = (f16*)(ws + 25165824);
  f16* wvb = (f16*)(ws + 33554432);
  f16* wpb = (f16*)(ws + 41943040);
  f16* qr  = (f16*)(ws + 50855936);         // [B,H,T,D]
  f16* kr  = (f16*)(ws + 67633152);         // [B,H,T,D]
  f16* vt  = (f16*)(ws + 84410368);         // [B,H,D,T] (direct from v-GEMM)
  f16* y   = xb;                            // aliases xb (dead after qkv GEMM)

  prep_kernel<<<dim3(2048), dim3(256), 0, stream>>>(
      x, xb, q_w, q_A, q_B, wqb, k_w, k_A, k_B, wkb, v_w, v_A, v_B, wvb, p_w,
      p_A, p_B, wpb, use_lora);

  GemmArgs qkv;
  qkv.A = xb;
  qkv.W[0] = wqb;  qkv.W[1] = wkb;  qkv.W[2] = wvb;
  qkv.bias[0] = q_b; qkv.bias[1] = k_b; qkv.bias[2] = v_b;
  qkv.out[0] = qr; qkv.out[1] = kr; qkv.out[2] = vt;
  qkv.mode[0] = 0; qkv.mode[1] = 1; qkv.mode[2] = 2;
  gemm2_kernel<<<dim3(512, 3), dim3(256), 65536, stream>>>(qkv, cosT, sinT);

  attn_kernel<<<dim3(16, 16, 2), dim3(256), 65536, stream>>>(qr, kr, vt, y);

  GemmArgs pp;
  pp.A = y;
  pp.W[0] = wpb;  pp.W[1] = wpb;  pp.W[2] = wpb;
  pp.bias[0] = p_b; pp.bias[1] = p_b; pp.bias[2] = p_b;
  pp.out[0] = d_out; pp.out[1] = d_out; pp.out[2] = d_out;
  pp.mode[0] = 3; pp.mode[1] = 3; pp.mode[2] = 3;
  gemm2_kernel<<<dim3(512, 1), dim3(256), 65536, stream>>>(pp, nullptr,
                                                           nullptr);
}